// Round 6
// baseline (330.821 us; speedup 1.0000x reference)
//
#include <hip/hip_runtime.h>
#include <hip/hip_bf16.h>
#include <math.h>

typedef short s16x8 __attribute__((ext_vector_type(8)));
typedef float f32x4 __attribute__((ext_vector_type(4)));

__device__ __forceinline__ float lrelu(float x) { return fmaxf(x, 0.2f * x); }
__device__ __forceinline__ float bflo(unsigned u) { return __uint_as_float(u << 16); }
__device__ __forceinline__ float bfhi(unsigned u) { return __uint_as_float(u & 0xffff0000u); }
__device__ __forceinline__ unsigned short f2bf(float f) {
    __hip_bfloat16 h = __float2bfloat16(f);
    return __builtin_bit_cast(unsigned short, h);
}
__device__ __forceinline__ f32x4 mfma_bf16(s16x8 a, s16x8 b, f32x4 c) {
    asm("v_mfma_f32_16x16x32_bf16 %0, %1, %2, %0" : "+v"(c) : "v"(a), "v"(b));
    return c;
}
__device__ __forceinline__ void unpack8(uint4 u, float* f) {
    f[0] = bflo(u.x); f[1] = bfhi(u.x);
    f[2] = bflo(u.y); f[3] = bfhi(u.y);
    f[4] = bflo(u.z); f[5] = bfhi(u.z);
    f[6] = bflo(u.w); f[7] = bfhi(u.w);
}

// ---------------- CSR build (sort edges by dst) ----------------
__global__ void degree_kernel(const int* __restrict__ dst, int* __restrict__ deg, int E) {
    int e = blockIdx.x * blockDim.x + threadIdx.x;
    if (e < E) atomicAdd(&deg[dst[e]], 1);
}

__global__ __launch_bounds__(1024) void scan_kernel(const int* __restrict__ deg,
                                                    int* __restrict__ off, int n) {
    __shared__ int wsum[16];
    __shared__ int s_carry;
    int t = threadIdx.x, lane = t & 63, w = t >> 6;
    if (t == 0) s_carry = 0;
    __syncthreads();
    for (int base = 0; base < n; base += 4096) {
        int i = base + t * 4;
        int4 v = make_int4(0, 0, 0, 0);
        if (i + 3 < n) v = *reinterpret_cast<const int4*>(&deg[i]);
        else {
            if (i < n) v.x = deg[i];
            if (i + 1 < n) v.y = deg[i + 1];
            if (i + 2 < n) v.z = deg[i + 2];
        }
        int tsum = v.x + v.y + v.z + v.w;
        int x = tsum;
        #pragma unroll
        for (int d = 1; d < 64; d <<= 1) { int y = __shfl_up(x, d); if (lane >= d) x += y; }
        if (lane == 63) wsum[w] = x;
        __syncthreads();
        if (w == 0 && lane < 16) {
            int y = wsum[lane];
            #pragma unroll
            for (int d = 1; d < 16; d <<= 1) { int z = __shfl_up(y, d); if (lane >= d) y += z; }
            wsum[lane] = y;
        }
        __syncthreads();
        int excl = s_carry + ((w == 0) ? 0 : wsum[w - 1]) + (x - tsum);
        if (i < n) off[i] = excl;
        if (i + 1 < n) off[i + 1] = excl + v.x;
        if (i + 2 < n) off[i + 2] = excl + v.x + v.y;
        if (i + 3 < n) off[i + 3] = excl + v.x + v.y + v.z;
        __syncthreads();
        if (t == 0) s_carry += wsum[15];
        __syncthreads();
    }
    if (t == 0) off[n] = s_carry;
}

__global__ void scatter_kernel(const int* __restrict__ src, const int* __restrict__ dst,
                               const int* __restrict__ off, int* __restrict__ cursor,
                               int* __restrict__ ssrc, int E) {
    int e = blockIdx.x * blockDim.x + threadIdx.x;
    if (e < E) {
        int d = dst[e];
        int pos = off[d] + atomicAdd(&cursor[d], 1);
        ssrc[pos] = src[e];
    }
}

// ---------------- weight prep: Wt[n][k] bf16, n-concat of Wl|Wr cols ----------------
__global__ void wt_prep_kernel(const float* __restrict__ Wl, const float* __restrict__ Wr,
                               unsigned short* __restrict__ Wt, int NOUT, int HALF) {
    int idx = blockIdx.x * 256 + threadIdx.x;  // idx = n*128 + k
    if (idx < NOUT * 128) {
        int n = idx >> 7, k = idx & 127;
        float v = (n < HALF) ? Wl[k * HALF + n] : Wr[k * HALF + (n - HALF)];
        Wt[idx] = f2bf(v);
    }
}

// ---------------- MFMA dual GEMM (unchanged from r5) ----------------
template <int NOUT, bool AFP32>
__global__ __launch_bounds__(256) void mfma_gemm_kernel(
    const void* __restrict__ A, const unsigned short* __restrict__ Wt,
    unsigned short* __restrict__ Cl, unsigned short* __restrict__ Cr, int nrows) {
    constexpr int HALF = NOUT / 2;
    constexpr int CT = NOUT / 64;
    __shared__ unsigned short As[64 * 128];
    int t = threadIdx.x, lane = t & 63, wave = t >> 6;
    int row_base = blockIdx.x * 64;
    int rows_here = nrows - row_base;
    #pragma unroll
    for (int it = 0; it < 4; ++it) {
        int q = it * 256 + t;
        int r = q >> 4, c8 = q & 15;
        int su = r * 16 + (c8 ^ (r & 7));
        s16x8 v = {0, 0, 0, 0, 0, 0, 0, 0};
        if (r < rows_here) {
            if (AFP32) {
                const float4* g = reinterpret_cast<const float4*>(
                    (const float*)A + ((size_t)(row_base + r)) * 128 + c8 * 8);
                float4 v0 = g[0], v1 = g[1];
                union { s16x8 s; unsigned short u[8]; } pk;
                pk.u[0] = f2bf(v0.x); pk.u[1] = f2bf(v0.y);
                pk.u[2] = f2bf(v0.z); pk.u[3] = f2bf(v0.w);
                pk.u[4] = f2bf(v1.x); pk.u[5] = f2bf(v1.y);
                pk.u[6] = f2bf(v1.z); pk.u[7] = f2bf(v1.w);
                v = pk.s;
            } else {
                v = *reinterpret_cast<const s16x8*>(
                    (const unsigned short*)A + ((size_t)(row_base + r)) * 128 + c8 * 8);
            }
        }
        reinterpret_cast<s16x8*>(As)[su] = v;
    }
    __syncthreads();
    int m16 = lane & 15, kg = lane >> 4;
    int colw = wave * (NOUT / 4);
    s16x8 bfr[CT][4];
    const s16x8* Wt16 = reinterpret_cast<const s16x8*>(Wt);
    #pragma unroll
    for (int ct = 0; ct < CT; ++ct)
        #pragma unroll
        for (int ks = 0; ks < 4; ++ks)
            bfr[ct][ks] = Wt16[(size_t)(colw + ct * 16 + m16) * 16 + ks * 4 + kg];
    f32x4 acc[4][CT];
    #pragma unroll
    for (int rt = 0; rt < 4; ++rt)
        #pragma unroll
        for (int ct = 0; ct < CT; ++ct) acc[rt][ct] = (f32x4){0.f, 0.f, 0.f, 0.f};
    const s16x8* As16 = reinterpret_cast<const s16x8*>(As);
    int sw = m16 & 7;
    #pragma unroll
    for (int rt = 0; rt < 4; ++rt) {
        int abase = (rt * 16 + m16) * 16;
        #pragma unroll
        for (int ks = 0; ks < 4; ++ks) {
            s16x8 af = As16[abase + ((ks * 4 + kg) ^ sw)];
            #pragma unroll
            for (int ct = 0; ct < CT; ++ct)
                acc[rt][ct] = mfma_bf16(af, bfr[ct][ks], acc[rt][ct]);
        }
    }
    int rq = kg * 4;
    #pragma unroll
    for (int rt = 0; rt < 4; ++rt) {
        #pragma unroll
        for (int ct = 0; ct < CT; ++ct) {
            int n = colw + ct * 16 + m16;
            unsigned short* Cp = (n < HALF) ? (Cl + n) : (Cr + (n - HALF));
            int row0 = row_base + rt * 16 + rq;
            #pragma unroll
            for (int i = 0; i < 4; ++i) {
                int row = row0 + i;
                if (row < nrows) Cp[(size_t)row * HALF] = f2bf(acc[rt][ct][i]);
            }
        }
    }
}

// ---------------- GAT layer 1: lane=(edge j=lane>>3, head h=lane&7) ----------------
// Each lane owns all 16 features of head h for edge slot j: logit is an
// in-register dot (no cross-lane in the edge loop); acc reduced across j
// once per node. 8 edges per wave-iteration.
__global__ __launch_bounds__(256) void gat1_kernel(
    const unsigned short* __restrict__ xl, const unsigned short* __restrict__ xr,
    const int* __restrict__ off, const int* __restrict__ ssrc,
    const float* __restrict__ att, const float* __restrict__ bias,
    const float* __restrict__ gamma, const float* __restrict__ beta,
    unsigned short* __restrict__ out, int n) {
    int lane = threadIdx.x & 63;
    int node = blockIdx.x * 4 + (threadIdx.x >> 6);
    if (node >= n) return;
    int j = lane >> 3, h = lane & 7;
    int fb = h * 16;
    float xrv[16], atv[16];
    {
        const unsigned short* xrow = xr + (size_t)node * 128 + fb;
        unpack8(*reinterpret_cast<const uint4*>(xrow), xrv);
        unpack8(*reinterpret_cast<const uint4*>(xrow + 8), xrv + 8);
        #pragma unroll
        for (int q = 0; q < 4; ++q) {
            float4 a = *reinterpret_cast<const float4*>(att + fb + q * 4);
            atv[q * 4] = a.x; atv[q * 4 + 1] = a.y; atv[q * 4 + 2] = a.z; atv[q * 4 + 3] = a.w;
        }
    }
    float acc[16], s = 0.f;
    #pragma unroll
    for (int c = 0; c < 16; ++c) acc[c] = 0.f;
    int beg = off[node], end = off[node + 1];
    for (int base = beg; base < end; base += 8) {
        int idx = base + j;
        bool valid = idx < end;
        int e = ssrc[valid ? idx : end - 1];
        const unsigned short* row = xl + (size_t)e * 128 + fb;
        uint4 A = *reinterpret_cast<const uint4*>(row);
        uint4 B = *reinterpret_cast<const uint4*>(row + 8);
        float xf[16];
        unpack8(A, xf);
        unpack8(B, xf + 8);
        float p0 = 0.f, p1 = 0.f, p2 = 0.f, p3 = 0.f;
        #pragma unroll
        for (int c = 0; c < 16; c += 4) {
            p0 += atv[c + 0] * lrelu(xf[c + 0] + xrv[c + 0]);
            p1 += atv[c + 1] * lrelu(xf[c + 1] + xrv[c + 1]);
            p2 += atv[c + 2] * lrelu(xf[c + 2] + xrv[c + 2]);
            p3 += atv[c + 3] * lrelu(xf[c + 3] + xrv[c + 3]);
        }
        float p = (p0 + p1) + (p2 + p3);
        float w = valid ? __expf(fminf(p, 60.f)) : 0.f;
        s += w;
        #pragma unroll
        for (int c = 0; c < 16; ++c) acc[c] += w * xf[c];
    }
    // reduce partials across the 8 edge-slots (lanes h, h+8, ..., h+56)
    #pragma unroll
    for (int d = 8; d <= 32; d <<= 1) {
        s += __shfl_xor(s, d);
        #pragma unroll
        for (int c = 0; c < 16; ++c) acc[c] += __shfl_xor(acc[c], d);
    }
    float inv = 1.f / (s + 1e-16f);
    float o[16];
    #pragma unroll
    for (int q = 0; q < 4; ++q) {
        float4 b = *reinterpret_cast<const float4*>(bias + fb + q * 4);
        o[q * 4 + 0] = acc[q * 4 + 0] * inv + b.x;
        o[q * 4 + 1] = acc[q * 4 + 1] * inv + b.y;
        o[q * 4 + 2] = acc[q * 4 + 2] * inv + b.z;
        o[q * 4 + 3] = acc[q * 4 + 3] * inv + b.w;
    }
    // LayerNorm over 128: lane sum over its 16, reduce across heads (xor 1,2,4)
    float tsum = 0.f;
    #pragma unroll
    for (int c = 0; c < 16; ++c) tsum += o[c];
    #pragma unroll
    for (int d = 1; d <= 4; d <<= 1) tsum += __shfl_xor(tsum, d);
    float mu = tsum * (1.f / 128.f);
    float vs = 0.f;
    #pragma unroll
    for (int c = 0; c < 16; ++c) { float dd = o[c] - mu; vs += dd * dd; }
    #pragma unroll
    for (int d = 1; d <= 4; d <<= 1) vs += __shfl_xor(vs, d);
    float rs = rsqrtf(vs * (1.f / 128.f) + 1e-5f);
    // each lane writes features fb + 2j, fb + 2j+1 (transposed map, 256B coalesced)
    int c0 = j * 2;
    float2 gb = *reinterpret_cast<const float2*>(gamma + fb + c0);
    float2 bb = *reinterpret_cast<const float2*>(beta + fb + c0);
    float y0 = (o[c0] - mu) * rs * gb.x + bb.x;
    float y1 = (o[c0 + 1] - mu) * rs * gb.y + bb.y;
    y0 = y0 > 0.f ? y0 : expm1f(y0);
    y1 = y1 > 0.f ? y1 : expm1f(y1);
    unsigned pk = (unsigned)f2bf(y0) | ((unsigned)f2bf(y1) << 16);
    *reinterpret_cast<unsigned*>(out + (size_t)node * 128 + fb + c0) = pk;
}

// ---------------- GAT layer 2: lane=(edge j=lane>>3, sub=lane&7) ----------------
// 8 feats/lane, 3-stage 8-lane p-reduce per edge-octet, per-node j-reduce.
__global__ __launch_bounds__(256) void gat2_kernel(
    const unsigned short* __restrict__ xl, const unsigned short* __restrict__ xr,
    const int* __restrict__ off, const int* __restrict__ ssrc,
    const float* __restrict__ att, const float* __restrict__ bias,
    const float* __restrict__ gamma, const float* __restrict__ beta,
    float* __restrict__ out, int n) {
    int lane = threadIdx.x & 63;
    int node = blockIdx.x * 4 + (threadIdx.x >> 6);
    if (node >= n) return;
    int j = lane >> 3, sub = lane & 7;
    int fb = sub * 8;
    float xrv[8], atv[8];
    unpack8(*reinterpret_cast<const uint4*>(xr + (size_t)node * 64 + fb), xrv);
    {
        float4 a0 = *reinterpret_cast<const float4*>(att + fb);
        float4 a1 = *reinterpret_cast<const float4*>(att + fb + 4);
        atv[0] = a0.x; atv[1] = a0.y; atv[2] = a0.z; atv[3] = a0.w;
        atv[4] = a1.x; atv[5] = a1.y; atv[6] = a1.z; atv[7] = a1.w;
    }
    float acc[8], s = 0.f;
    #pragma unroll
    for (int c = 0; c < 8; ++c) acc[c] = 0.f;
    int beg = off[node], end = off[node + 1];
    for (int base = beg; base < end; base += 8) {
        int idx = base + j;
        bool valid = idx < end;
        int e = ssrc[valid ? idx : end - 1];
        uint4 A = *reinterpret_cast<const uint4*>(xl + (size_t)e * 64 + fb);
        float xf[8];
        unpack8(A, xf);
        float p0 = 0.f, p1 = 0.f;
        #pragma unroll
        for (int c = 0; c < 8; c += 2) {
            p0 += atv[c] * lrelu(xf[c] + xrv[c]);
            p1 += atv[c + 1] * lrelu(xf[c + 1] + xrv[c + 1]);
        }
        float p = p0 + p1;
        p += __shfl_xor(p, 1);
        p += __shfl_xor(p, 2);
        p += __shfl_xor(p, 4);
        float w = valid ? __expf(fminf(p, 60.f)) : 0.f;
        s += w;
        #pragma unroll
        for (int c = 0; c < 8; ++c) acc[c] += w * xf[c];
    }
    #pragma unroll
    for (int d = 8; d <= 32; d <<= 1) {
        s += __shfl_xor(s, d);
        #pragma unroll
        for (int c = 0; c < 8; ++c) acc[c] += __shfl_xor(acc[c], d);
    }
    float inv = 1.f / (s + 1e-16f);
    float o[8];
    {
        float4 b0 = *reinterpret_cast<const float4*>(bias + fb);
        float4 b1 = *reinterpret_cast<const float4*>(bias + fb + 4);
        o[0] = acc[0] * inv + b0.x; o[1] = acc[1] * inv + b0.y;
        o[2] = acc[2] * inv + b0.z; o[3] = acc[3] * inv + b0.w;
        o[4] = acc[4] * inv + b1.x; o[5] = acc[5] * inv + b1.y;
        o[6] = acc[6] * inv + b1.z; o[7] = acc[7] * inv + b1.w;
    }
    float tsum = 0.f;
    #pragma unroll
    for (int c = 0; c < 8; ++c) tsum += o[c];
    #pragma unroll
    for (int d = 1; d <= 4; d <<= 1) tsum += __shfl_xor(tsum, d);
    float mu = tsum * (1.f / 64.f);
    float vs = 0.f;
    #pragma unroll
    for (int c = 0; c < 8; ++c) { float dd = o[c] - mu; vs += dd * dd; }
    #pragma unroll
    for (int d = 1; d <= 4; d <<= 1) vs += __shfl_xor(vs, d);
    float rs = rsqrtf(vs * (1.f / 64.f) + 1e-5f);
    // lane writes feature fb + j (transposed map, 256B coalesced)
    float yv = (o[j] - mu) * rs * gamma[fb + j] + beta[fb + j];
    out[(size_t)node * 64 + fb + j] = yv;
}

extern "C" void kernel_launch(void* const* d_in, const int* in_sizes, int n_in,
                              void* d_out, int out_size, void* d_ws, size_t ws_size,
                              hipStream_t stream) {
    const float* x = (const float*)d_in[0];
    const int* ei = (const int*)d_in[1];
    const float* Wl1 = (const float*)d_in[2];
    const float* Wr1 = (const float*)d_in[3];
    const float* att1 = (const float*)d_in[4];
    const float* bias1 = (const float*)d_in[5];
    const float* g1 = (const float*)d_in[6];
    const float* b1 = (const float*)d_in[7];
    const float* Wl2 = (const float*)d_in[8];
    const float* Wr2 = (const float*)d_in[9];
    const float* att2 = (const float*)d_in[10];
    const float* bias2 = (const float*)d_in[11];
    const float* g2 = (const float*)d_in[12];
    const float* b2 = (const float*)d_in[13];
    float* out = (float*)d_out;

    const int N = in_sizes[0] / 128;
    const int E = in_sizes[1] / 2;
    const int* src = ei;
    const int* dstp = ei + E;

    char* p = (char*)d_ws;
    auto alloc = [&](size_t bytes) -> char* {
        char* r = p;
        p += (bytes + 255) & ~(size_t)255;
        return r;
    };
    int* deg = (int*)alloc((size_t)N * 4);
    int* cursor = (int*)alloc((size_t)N * 4);
    int* off = (int*)alloc((size_t)(N + 1) * 4);
    int* ssrc = (int*)alloc((size_t)E * 4);
    unsigned short* Wt1 = (unsigned short*)alloc(256 * 128 * 2);
    unsigned short* Wt2 = (unsigned short*)alloc(128 * 128 * 2);
    unsigned short* bufA = (unsigned short*)alloc((size_t)N * 128 * 2);
    unsigned short* bufB = (unsigned short*)alloc((size_t)N * 128 * 2);
    unsigned short* h1u = (unsigned short*)alloc((size_t)N * 128 * 2);

    hipMemsetAsync(deg, 0, (size_t)N * 4, stream);
    hipMemsetAsync(cursor, 0, (size_t)N * 4, stream);
    degree_kernel<<<(E + 255) / 256, 256, 0, stream>>>(dstp, deg, E);
    wt_prep_kernel<<<(256 * 128 + 255) / 256, 256, 0, stream>>>(Wl1, Wr1, Wt1, 256, 128);
    wt_prep_kernel<<<(128 * 128 + 255) / 256, 256, 0, stream>>>(Wl2, Wr2, Wt2, 128, 64);
    scan_kernel<<<1, 1024, 0, stream>>>(deg, off, N);
    scatter_kernel<<<(E + 255) / 256, 256, 0, stream>>>(src, dstp, off, cursor, ssrc, E);

    int gblocks = (N + 63) / 64;
    mfma_gemm_kernel<256, true><<<gblocks, 256, 0, stream>>>(x, Wt1, bufA, bufB, N);
    gat1_kernel<<<(N + 3) / 4, 256, 0, stream>>>(bufA, bufB, off, ssrc, att1, bias1, g1, b1, h1u, N);
    mfma_gemm_kernel<128, false><<<gblocks, 256, 0, stream>>>(h1u, Wt2, bufA, bufB, N);
    gat2_kernel<<<(N + 3) / 4, 256, 0, stream>>>(bufA, bufB, off, ssrc, att2, bias2, g2, b2, out, N);
}